// Round 8
// baseline (12337.101 us; speedup 1.0000x reference)
//
#include <hip/hip_runtime.h>

#define T_LEN 2048

typedef _Float16 f16x8 __attribute__((ext_vector_type(8)));
typedef float f32x4 __attribute__((ext_vector_type(4)));
typedef unsigned int u32;

__device__ __forceinline__ float sigm(float v) { return 1.f / (1.f + __expf(-v)); }

// XOR-swizzled address into an A tile [16 seq][512 k] f16 (row stride 1024B).
__device__ __forceinline__ void* swzA(_Float16* base, int row, int k) {
  int byte = row * 1024 + k * 2;
  byte ^= (row & 7) << 4;
  return (void*)((char*)base + byte);
}

// local-mailbox ops: plain store (write-through -> this XCD's L2);
// sc0 load (L1-bypass, served by the shared L2 if line is present).
__device__ __forceinline__ void lstore(u32* p, u32 v) {
  asm volatile("global_store_dword %0, %1, off" ::"v"(p), "v"(v) : "memory");
}
__device__ __forceinline__ void issue3_sc0(const u32* p1, const u32* p2,
                                           const u32* p3, u32& a, u32& b,
                                           u32& c) {
  asm volatile(
      "global_load_dword %0, %3, off sc0\n\t"
      "global_load_dword %1, %4, off sc0\n\t"
      "global_load_dword %2, %5, off sc0"
      : "=&v"(a), "=&v"(b), "=&v"(c)
      : "v"(p1), "v"(p2), "v"(p3)
      : "memory");
}
__device__ __forceinline__ void wait_vm0(u32& a, u32& b, u32& c) {
  asm volatile("s_waitcnt vmcnt(0)" : "+v"(a), "+v"(b), "+v"(c)::"memory");
}

// Grid: 32 WGs x 1024 thr; active iff (bid&7)<4. group g=bid&7 {dir,bh}: 16 seqs;
// member m=bid>>3 owns dims [64m..64m+63]; members at bids {g,g+8,g+16,g+24}
// == g (mod 8) -> same XCD under round-robin dispatch (speed-only assumption).
// Wave w owns 4 dims x all 4 gate parts. KERNEL part order is [i,f,j,o]
// (shuffle network + bias fold built for it); reference W column blocks are
// [i,j,f,o] -> map kernel part p to column block qblk = {0,2,1,3}[p].
// Exchange line: u32 {stamp16 | f16 h}; stamp==want ==> data correct (only
// writers: zeroing(stamp 0) and producer(stamp t+1)), so the fast L2 mailbox
// is safe under ANY placement; a thread failing 64 local polls permanently
// falls back to the MALL mailbox (proven R3-R6).
__global__ __launch_bounds__(1024, 4) void bilstm_kernel(
    const float* __restrict__ x, const float* __restrict__ Wfw,
    const float* __restrict__ bfw, const float* __restrict__ Wbw,
    const float* __restrict__ bbw, float* __restrict__ out,
    u32* __restrict__ gmbox, u32* __restrict__ lmbox, u32* __restrict__ flags) {
  const int bid = blockIdx.x;
  if ((bid & 7) >= 4) return;
  const int g = bid & 7;
  const int m = bid >> 3;
  const int dir = g >> 1, bh = g & 1;
  const int tid = threadIdx.x;
  const int w = tid >> 6;
  const int lane = tid & 63;
  const int l15 = lane & 15, l4 = lane >> 4;
  const int p = l15 >> 2;

  const float* W = dir ? Wbw : Wfw;
  const float* bias = dir ? bbw : bfw;

  __shared__ _Float16 A[2][16 * 512];  // 32KB: double-buffered [seq][x|h]

  // ---- weights: kernel part p -> reference column block qblk ----
  const int qblk = (p == 1) ? 2 : ((p == 2) ? 1 : p);  // [i,f,j,o] -> [i,j,f,o]
  const int gcol = qblk * 256 + 64 * m + 4 * w + (l15 & 3);
  f16x8 wB[16];
#pragma unroll
  for (int kk = 0; kk < 16; ++kk) {
    const int kb = kk * 32 + l4 * 8;
    f16x8 hld;
#pragma unroll
    for (int j = 0; j < 8; ++j) hld[j] = (_Float16)W[(kb + j) * 1024 + gcol];
    wB[kk] = hld;
  }
  const float bcol = bias[gcol] + ((p == 1) ? 1.f : 0.f);  // forget bias (qblk 2)

  u32* Gm = gmbox + g * (2 * 16 * 256);
  u32* Lm = lmbox + g * (2 * 16 * 256);

  // poll mapping: thread covers (seq cs=w, dim cd=lane) -> 3 peer dims
  const int cs = w, cd = lane;
  const int pd1 = 64 * ((m + 1) & 3) + cd;
  const int pd2 = 64 * ((m + 2) & 3) + cd;
  const int pd3 = 64 * ((m + 3) & 3) + cd;

  // ---- init: zero the local lines THIS thread polls (lands in OUR L2) ----
#pragma unroll
  for (int b = 0; b < 2; ++b) {
    u32* Lb = Lm + (b * 16 + cs) * 256;
    lstore(Lb + pd1, 0u);
    lstore(Lb + pd2, 0u);
    lstore(Lb + pd3, 0u);
  }
  {  // zero A[0] h-half
    uint2 z = {0u, 0u};
    *(uint2*)swzA(A[0], cs, 256 + 4 * cd) = z;
  }
  __syncthreads();  // drains all waves' zero stores (vmcnt0 before barrier)
  // handshake: no publish before all members finished zeroing
  if (tid == 0) {
    __hip_atomic_store(flags + g * 4 + m, 1, __ATOMIC_RELEASE,
                       __HIP_MEMORY_SCOPE_AGENT);
    int got;
    do {
      got = 0;
      for (int q = 0; q < 4; ++q)
        got += __hip_atomic_load(flags + g * 4 + q, __ATOMIC_ACQUIRE,
                                 __HIP_MEMORY_SCOPE_AGENT);
    } while (got < 4);
  }
  __syncthreads();

  // prologue: prefetch x_0
  const int tx0 = dir ? (T_LEN - 1) : 0;
  f32x4 xv = *(const f32x4*)(x + (((bh * 16 + cs) * T_LEN + tx0) << 8) + 4 * cd);

  float c[4] = {0.f, 0.f, 0.f, 0.f};
  unsigned short hb[4] = {0, 0, 0, 0};  // own h(t-1) f16 bits (p0 lanes)
  bool use_global = false;
  const bool s1b = (l15 & 4) != 0;
  const bool s2b = (l15 & 8) != 0;

  for (int t = 0; t < T_LEN; ++t) {
    const int bufc = t & 1;
    const int tx = dir ? (T_LEN - 1 - t) : t;
    _Float16* Ab = A[bufc];

    // ---- stage x_t (regs -> A x-half) ----
    {
      union { _Float16 h4[4]; uint2 q; } ux;
#pragma unroll
      for (int j = 0; j < 4; ++j) ux.h4[j] = (_Float16)xv[j];
      *(uint2*)swzA(Ab, cs, 4 * cd) = ux.q;
    }

    u32 s1 = 0, s2 = 0, s3 = 0;
    const u32 want = (u32)t;
    u32* Lp = Lm + ((bufc ^ 1) * 16 + cs) * 256;
    u32* Gp = Gm + ((bufc ^ 1) * 16 + cs) * 256;
    if (t > 0) {
      // stage own h(t-1) from regs (no mailbox round-trip)
      if (p == 0) {
        const int kd = 256 + 64 * m + 4 * w + l15;
#pragma unroll
        for (int v = 0; v < 4; ++v)
          *(unsigned short*)swzA(Ab, 4 * l4 + v, kd) = hb[v];
      }
      if (!use_global) issue3_sc0(Lp + pd1, Lp + pd2, Lp + pd3, s1, s2, s3);
    }

    // ---- prefetch x_{t+1} ----
    {
      const int tn = (t + 1 < T_LEN) ? t + 1 : t;
      const int txn = dir ? (T_LEN - 1 - tn) : tn;
      xv = *(const f32x4*)(x + (((bh * 16 + cs) * T_LEN + txn) << 8) + 4 * cd);
    }

    if (t > 0) {
      if (!use_global) {
        wait_vm0(s1, s2, s3);
        int tries = 0;
        while ((s1 >> 16) != want || (s2 >> 16) != want || (s3 >> 16) != want) {
          if (++tries > 64) { use_global = true; break; }  // wrong XCD: permanent
          issue3_sc0(Lp + pd1, Lp + pd2, Lp + pd3, s1, s2, s3);
          wait_vm0(s1, s2, s3);
        }
      }
      if (use_global) {
        for (;;) {
          s1 = __hip_atomic_load(Gp + pd1, __ATOMIC_RELAXED, __HIP_MEMORY_SCOPE_AGENT);
          s2 = __hip_atomic_load(Gp + pd2, __ATOMIC_RELAXED, __HIP_MEMORY_SCOPE_AGENT);
          s3 = __hip_atomic_load(Gp + pd3, __ATOMIC_RELAXED, __HIP_MEMORY_SCOPE_AGENT);
          if ((s1 >> 16) == want && (s2 >> 16) == want && (s3 >> 16) == want) break;
        }
      }
      *(unsigned short*)swzA(Ab, cs, 256 + pd1) = (unsigned short)(s1 & 0xffffu);
      *(unsigned short*)swzA(Ab, cs, 256 + pd2) = (unsigned short)(s2 & 0xffffu);
      *(unsigned short*)swzA(Ab, cs, 256 + pd3) = (unsigned short)(s3 & 0xffffu);
    }
    __syncthreads();  // B1 (the only barrier per step)

    // ---- MFMA over [x|h] (K=512), acc seeded with bias ----
    f32x4 acc = {bcol, bcol, bcol, bcol};
#pragma unroll
    for (int kk = 0; kk < 16; ++kk) {
      f16x8 a = *(const f16x8*)swzA(Ab, l15, kk * 32 + l4 * 8);
      acc = __builtin_amdgcn_mfma_f32_16x16x32_f16(a, wB[kk], acc, 0, 0, 0);
    }

    // ---- in-register cell via part-alignment network, then publish ----
    const u32 stamp = ((u32)(t + 1)) << 16;
    const int dim64 = 64 * m + 4 * w + l15;  // publishes use l15<4 only
    u32* Lq = Lm + (bufc * 16) * 256;
    u32* Gq = Gm + (bufc * 16) * 256;
#pragma unroll
    for (int v = 0; v < 4; ++v) {
      float A0 = acc[v];
      float A1 = __shfl_xor(A0, 4);
      float A2 = __shfl_xor(A0, 8);
      float A3 = __shfl_xor(A1, 8);
      float B0 = s1b ? A1 : A0, B1 = s1b ? A0 : A1;
      float B2 = s1b ? A3 : A2, B3 = s1b ? A2 : A3;
      float gi = s2b ? B2 : B0;   // part 0 = i
      float gf = s2b ? B3 : B1;   // part 1 = f (qblk 2, +1 folded)
      float gj = s2b ? B0 : B2;   // part 2 = j (qblk 1)
      float go = s2b ? B1 : B3;   // part 3 = o
      c[v] = c[v] * sigm(gf) + sigm(gi) * (2.f * sigm(gj + gj) - 1.f);
      float h = (2.f * sigm(c[v] + c[v]) - 1.f) * sigm(go);
      if (p == 0) {
        union { _Float16 hf; unsigned short us; } cv;
        cv.hf = (_Float16)h;
        hb[v] = cv.us;
        const int seq = 4 * l4 + v;
        const int li = seq * 256 + dim64;
        lstore(Lq + li, stamp | (u32)cv.us);                // L2 fast path
        __hip_atomic_store(Gq + li, stamp | (u32)cv.us,     // MALL fallback
                           __ATOMIC_RELAXED, __HIP_MEMORY_SCOPE_AGENT);
        __builtin_nontemporal_store(
            h, out + (((bh * 16 + seq) * T_LEN + tx) << 9) + dir * 256 + dim64);
      }
    }
  }
}

extern "C" void kernel_launch(void* const* d_in, const int* in_sizes, int n_in,
                              void* d_out, int out_size, void* d_ws,
                              size_t ws_size, hipStream_t stream) {
  const float* x = (const float*)d_in[0];
  const float* Wfw = (const float*)d_in[1];
  const float* bfw = (const float*)d_in[2];
  const float* Wbw = (const float*)d_in[3];
  const float* bbw = (const float*)d_in[4];
  float* out = (float*)d_out;

  // ws: [0,128K) global (MALL) mbox  [128K,+64B) flags  [132K,260K) local mbox
  u32* gmbox = (u32*)d_ws;
  u32* flags = (u32*)((char*)d_ws + 128 * 1024);
  u32* lmbox = (u32*)((char*)d_ws + 132 * 1024);
  (void)hipMemsetAsync(d_ws, 0, 132 * 1024, stream);  // gmbox + flags only

  bilstm_kernel<<<dim3(32), dim3(1024), 0, stream>>>(x, Wfw, bfw, Wbw, bbw, out,
                                                     gmbox, lmbox, flags);
}

// Round 9
// 4814.512 us; speedup vs baseline: 2.5625x; 2.5625x over previous
//
#include <hip/hip_runtime.h>

#define T_LEN 2048

typedef _Float16 f16x8 __attribute__((ext_vector_type(8)));
typedef float f32x4 __attribute__((ext_vector_type(4)));
typedef unsigned int u32;

__device__ __forceinline__ float sigm(float v) { return 1.f / (1.f + __expf(-v)); }

// XOR-swizzled address into A tile [16 seq][512 k] f16 (row stride 1024B).
__device__ __forceinline__ void* swzA(_Float16* base, int row, int k) {
  int byte = row * 1024 + k * 2;
  byte ^= (row & 7) << 4;
  return (void*)((char*)base + byte);
}

// Batched MALL poll: 3 independent device-coherent loads (sc0 sc1 = bypass
// L1+L2, read the coherent point), ONE vmcnt wait -> 1 RTT per iteration.
__device__ __forceinline__ void issue3_mall(const u32* p1, const u32* p2,
                                            const u32* p3, u32& a, u32& b,
                                            u32& c) {
  asm volatile(
      "global_load_dword %0, %3, off sc0 sc1\n\t"
      "global_load_dword %1, %4, off sc0 sc1\n\t"
      "global_load_dword %2, %5, off sc0 sc1"
      : "=&v"(a), "=&v"(b), "=&v"(c)
      : "v"(p1), "v"(p2), "v"(p3)
      : "memory");
}
__device__ __forceinline__ void wait3(u32& a, u32& b, u32& c) {
  asm volatile("s_waitcnt vmcnt(0)" : "+v"(a), "+v"(b), "+v"(c)::"memory");
}

// Grid: 16 WGs x 1024 threads (R5 backbone). group g = bid&3 {dir,bh} -> 16 seqs;
// member m = bid>>2 owns h-dims [64m..64m+63]. Wave w: part p=w>>2, 16 cols at
// p*256 + 64m + (w&3)*16. Exchange: u32 {stamp16|h-f16} per (seq,dim),
// double-buffered by t&1, MALL mailbox (agent store, sc0sc1 load).
__global__ __launch_bounds__(1024, 4) void bilstm_kernel(
    const float* __restrict__ x, const float* __restrict__ Wfw,
    const float* __restrict__ bfw, const float* __restrict__ Wbw,
    const float* __restrict__ bbw, float* __restrict__ out,
    u32* __restrict__ hglob) {
  const int g = blockIdx.x & 3;
  const int m = blockIdx.x >> 2;
  const int dir = g >> 1, bh = g & 1;
  const int tid = threadIdx.x;
  const int w = tid >> 6;
  const int lane = tid & 63;
  const int l15 = lane & 15, l4 = lane >> 4;

  const float* W = dir ? Wbw : Wfw;
  const float* bias = dir ? bbw : bfw;

  __shared__ _Float16 Alds[16 * 512];  // 16KB swizzled [seq][k<256:x, k>=256:h]
  __shared__ float Glds[16 * 260];     // gates [seq][256 cols], stride 260

  // ---- weight slice: one 16-col tile x K=512 -> 64 VGPRs ----
  const int p = w >> 2;
  const int cbase = p * 64 + (w & 3) * 16;  // col within WG's 256
  const int gcol = p * 256 + 64 * m + (w & 3) * 16 + l15;
  f16x8 wB[16];
#pragma unroll
  for (int kk = 0; kk < 16; ++kk) {
    const int kb = kk * 32 + l4 * 8;
    f16x8 h;
#pragma unroll
    for (int j = 0; j < 8; ++j) h[j] = (_Float16)W[(kb + j) * 1024 + gcol];
    wB[kk] = h;
  }
  const float bcol = bias[gcol] + ((p == 2) ? 1.f : 0.f);  // forget bias folded

  // ---- per-thread cell/stage/poll mapping: (seq cs, dim cd) ----
  const int cs = tid >> 6;  // 0..15
  const int cd = tid & 63;  // 0..63
  float c = 0.f;

  u32* Hg = hglob + g * (2 * 16 * 256);
  const int pd1 = 64 * ((m + 1) & 3) + cd;
  const int pd2 = 64 * ((m + 2) & 3) + cd;
  const int pd3 = 64 * ((m + 3) & 3) + cd;
  u32* my0 = Hg + (0 * 16 + cs) * 256 + 64 * m + cd;
  u32* my1 = Hg + (1 * 16 + cs) * 256 + 64 * m + cd;

  // prologue: zero A h-half, prefetch x_0
  {
    uint2 z = {0u, 0u};
    *(uint2*)swzA(Alds, cs, 256 + 4 * cd) = z;
  }
  const int tx0 = dir ? (T_LEN - 1) : 0;
  f32x4 xv = *(const f32x4*)(x + (((bh * 16 + cs) * T_LEN + tx0) << 8) + 4 * cd);

  for (int t = 0; t < T_LEN; ++t) {
    const int tx = dir ? (T_LEN - 1 - t) : t;

    // ---- stage x_t (4 f32 -> 4 f16, one 8B LDS write) ----
    {
      union { _Float16 h4[4]; uint2 q; } ux;
#pragma unroll
      for (int j = 0; j < 4; ++j) ux.h4[j] = (_Float16)xv[j];
      *(uint2*)swzA(Alds, cs, 4 * cd) = ux.q;
    }

    // ---- issue first poll sample BEFORE the barrier (max overlap) ----
    const u32 want = (u32)t;
    const u32* Hp = Hg + (((t & 1) ^ 1) * 16 + cs) * 256;
    u32 s1 = 0, s2 = 0, s3 = 0;
    if (t > 0) issue3_mall(Hp + pd1, Hp + pd2, Hp + pd3, s1, s2, s3);

    __syncthreads();  // B1: x staged; own-h(t-1) staged at cell time (pre-B1)

    // ---- prefetch x_{t+1} ----
    {
      const int tn = (t + 1 < T_LEN) ? t + 1 : t;
      const int txn = dir ? (T_LEN - 1 - tn) : tn;
      xv = *(const f32x4*)(x + (((bh * 16 + cs) * T_LEN + txn) << 8) + 4 * cd);
    }

    // ---- pre-detect MFMAs: x tiles (0..7) + OWN h pair (8+2m, 9+2m) ----
    f32x4 acc = {bcol, bcol, bcol, bcol};
#pragma unroll
    for (int kk = 0; kk < 8; ++kk) {
      f16x8 a = *(const f16x8*)swzA(Alds, l15, kk * 32 + l4 * 8);
      acc = __builtin_amdgcn_mfma_f32_16x16x32_f16(a, wB[kk], acc, 0, 0, 0);
    }
#pragma unroll
    for (int q = 0; q < 4; ++q) {
      if (q == m) {  // uniform branch; compile-time register indices
        f16x8 a0 = *(const f16x8*)swzA(Alds, l15, (8 + 2 * q) * 32 + l4 * 8);
        acc = __builtin_amdgcn_mfma_f32_16x16x32_f16(a0, wB[8 + 2 * q], acc, 0, 0, 0);
        f16x8 a1 = *(const f16x8*)swzA(Alds, l15, (9 + 2 * q) * 32 + l4 * 8);
        acc = __builtin_amdgcn_mfma_f32_16x16x32_f16(a1, wB[9 + 2 * q], acc, 0, 0, 0);
      }
    }

    // ---- detect peers' h (batched 1-RTT poll iterations), stage to LDS ----
    if (t > 0) {
      wait3(s1, s2, s3);
      while ((s1 >> 16) != want || (s2 >> 16) != want || (s3 >> 16) != want) {
        issue3_mall(Hp + pd1, Hp + pd2, Hp + pd3, s1, s2, s3);
        wait3(s1, s2, s3);
      }
      *(unsigned short*)swzA(Alds, cs, 256 + pd1) = (unsigned short)(s1 & 0xffffu);
      *(unsigned short*)swzA(Alds, cs, 256 + pd2) = (unsigned short)(s2 & 0xffffu);
      *(unsigned short*)swzA(Alds, cs, 256 + pd3) = (unsigned short)(s3 & 0xffffu);
    }
    __syncthreads();  // B2: peer h staged

    // ---- post-detect MFMAs: the 3 peer h pairs (6 tiles) ----
#pragma unroll
    for (int q = 0; q < 4; ++q) {
      if (q != m) {
        f16x8 a0 = *(const f16x8*)swzA(Alds, l15, (8 + 2 * q) * 32 + l4 * 8);
        acc = __builtin_amdgcn_mfma_f32_16x16x32_f16(a0, wB[8 + 2 * q], acc, 0, 0, 0);
        f16x8 a1 = *(const f16x8*)swzA(Alds, l15, (9 + 2 * q) * 32 + l4 * 8);
        acc = __builtin_amdgcn_mfma_f32_16x16x32_f16(a1, wB[9 + 2 * q], acc, 0, 0, 0);
      }
    }

    // ---- gates -> LDS transpose (C/D: col=l15, row=4*l4+v) ----
    {
      float* gw = Glds + cbase + l15;
      const int r = l4 * 4;
#pragma unroll
      for (int v = 0; v < 4; ++v) gw[(r + v) * 260] = acc[v];
    }
    __syncthreads();  // B3: gates ready

    // ---- LSTM cell: thread owns (cs, cd) ----
    const float* Gp = Glds + cs * 260 + cd;
    const float gi = Gp[0 * 64], gj = Gp[1 * 64], gf = Gp[2 * 64], go = Gp[3 * 64];
    c = c * sigm(gf) + sigm(gi) * (2.f * sigm(gj + gj) - 1.f);
    const float h = (2.f * sigm(c + c) - 1.f) * sigm(go);

    // publish (coalesced 256B per wave), stage own h locally, store out
    union { _Float16 hf; unsigned short us; } cv;
    cv.hf = (_Float16)h;
    __hip_atomic_store((t & 1) ? my1 : my0, (((u32)(t + 1)) << 16) | (u32)cv.us,
                       __ATOMIC_RELAXED, __HIP_MEMORY_SCOPE_AGENT);
    *(unsigned short*)swzA(Alds, cs, 256 + 64 * m + cd) = cv.us;
    __builtin_nontemporal_store(
        h, out + (((bh * 16 + cs) * T_LEN + tx) << 9) + dir * 256 + 64 * m + cd);
  }
}

extern "C" void kernel_launch(void* const* d_in, const int* in_sizes, int n_in,
                              void* d_out, int out_size, void* d_ws,
                              size_t ws_size, hipStream_t stream) {
  const float* x = (const float*)d_in[0];
  const float* Wfw = (const float*)d_in[1];
  const float* bfw = (const float*)d_in[2];
  const float* Wbw = (const float*)d_in[3];
  const float* bbw = (const float*)d_in[4];
  float* out = (float*)d_out;

  // ws: 4 groups x 2 bufs x 16 seq x 256 dims x u32 = 128KB stamped h-lines
  u32* hglob = (u32*)d_ws;
  (void)hipMemsetAsync(hglob, 0, 4 * 2 * 16 * 256 * sizeof(u32), stream);

  bilstm_kernel<<<dim3(16), dim3(1024), 0, stream>>>(x, Wfw, bfw, Wbw, bbw, out,
                                                     hglob);
}